// Round 1
// baseline (186.326 us; speedup 1.0000x reference)
//
#include <hip/hip_runtime.h>

// SMPL forward: B=512 batches, V=6890 verts, NB=10 shape dims, NJ=24 joints, 9 extra joints.
// Output fp32 (B, V+33, 3).

#define BATCH 512
#define NV 6890
#define NBD 10
#define NJ 24
#define NEXTRA 9
#define NOUT (NV + NJ + NEXTRA)   // 6923
#define VBLK ((NV + 255) / 256)   // 27
#define BPB 4                     // batches per block in LBS kernel

__constant__ int c_par[NJ] = {-1,0,0,0,1,2,3,4,5,6,7,8,9,9,9,12,13,14,16,17,18,19,20,21};

// ---------------------------------------------------------------------------
// Kernel A: batch-independent regressor precompute.
// jtjs[j][0:3]   = Jt[j][k]      = sum_v Jreg[j,v] * v_template[v,k]
// jtjs[j][3+k*10+l] = JS[j][k][l] = sum_v Jreg[j,v] * shapedirs[v,k,l]
// grid (VBLK, NJ), block 256. Atomic-accumulated into zeroed ws.
// ---------------------------------------------------------------------------
__global__ __launch_bounds__(256) void precompute_kernel(
    const float* __restrict__ jreg,
    const float* __restrict__ smpl_t,
    const float* __restrict__ smil_t,
    const float* __restrict__ sdirs,
    const float* __restrict__ msc,
    float* __restrict__ jtjs)
{
    const int j = blockIdx.y;
    const int v = blockIdx.x * 256 + threadIdx.x;
    const float s = msc[0];

    float acc[33];
#pragma unroll
    for (int i = 0; i < 33; ++i) acc[i] = 0.f;

    if (v < NV) {
        const float w = jreg[j * NV + v];
#pragma unroll
        for (int k = 0; k < 3; ++k) {
            float vt = s * smpl_t[v * 3 + k] + (1.f - s) * smil_t[v * 3 + k];
            acc[k] = w * vt;
        }
        const float2* sd2 = (const float2*)(sdirs + (size_t)v * 30);
#pragma unroll
        for (int i = 0; i < 15; ++i) {
            float2 x = sd2[i];
            acc[3 + 2 * i]     = w * x.x;
            acc[3 + 2 * i + 1] = w * x.y;
        }
    }

    // butterfly reduce over 64-lane wave
#pragma unroll
    for (int i = 0; i < 33; ++i) {
        float x = acc[i];
        for (int off = 32; off; off >>= 1) x += __shfl_xor(x, off, 64);
        acc[i] = x;
    }

    __shared__ float red[4][33];
    const int lane = threadIdx.x & 63, wv = threadIdx.x >> 6;
    if (lane == 0) {
#pragma unroll
        for (int i = 0; i < 33; ++i) red[wv][i] = acc[i];
    }
    __syncthreads();
    if (threadIdx.x < 33) {
        float sum = red[0][threadIdx.x] + red[1][threadIdx.x]
                  + red[2][threadIdx.x] + red[3][threadIdx.x];
        atomicAdd(&jtjs[j * 33 + threadIdx.x], sum);
    }
}

// ---------------------------------------------------------------------------
// Kernel B: per-batch joints — Rodrigues, kinematic chain, A matrices.
// grid BATCH, block 64 (one wave). Lanes 0..23 own joint j.
// Writes A[b,j] (3x4 row-major, 12 floats) to wsA and posed joints (+transl) to out.
// ---------------------------------------------------------------------------
__global__ __launch_bounds__(64) void joints_kernel(
    const float* __restrict__ betas,
    const float* __restrict__ body_pose,
    const float* __restrict__ glob_or,
    const float* __restrict__ transl,
    const float* __restrict__ jtjs,
    float* __restrict__ wsA,
    float* __restrict__ out)
{
    const int b = blockIdx.x;
    const int j = threadIdx.x;

    __shared__ float sJ[NJ][3];     // J_shaped
    __shared__ float mats[NJ][12];  // [R | rel_t] 3x4 row-major
    __shared__ float chain[NJ][12];
    __shared__ float sbeta[NBD + 1];

    if (threadIdx.x < NBD + 1) sbeta[threadIdx.x] = betas[b * (NBD + 1) + threadIdx.x];
    __syncthreads();

    if (j < NJ) {
        const float beta0 = sbeta[0];
        // J_shaped[b,j,k]
#pragma unroll
        for (int k = 0; k < 3; ++k) {
            float a = jtjs[j * 33 + k];
#pragma unroll
            for (int l = 0; l < NBD; ++l) a = fmaf(sbeta[1 + l], jtjs[j * 33 + 3 + k * 10 + l], a);
            sJ[j][k] = a * beta0;
        }
        // Rodrigues. angle uses rvec+1e-8 per-component; axis uses raw rvec.
        float rx, ry, rz;
        if (j == 0) {
            rx = glob_or[b * 3 + 0]; ry = glob_or[b * 3 + 1]; rz = glob_or[b * 3 + 2];
        } else {
            rx = body_pose[b * 69 + (j - 1) * 3 + 0];
            ry = body_pose[b * 69 + (j - 1) * 3 + 1];
            rz = body_pose[b * 69 + (j - 1) * 3 + 2];
        }
        float ex = rx + 1e-8f, ey = ry + 1e-8f, ez = rz + 1e-8f;
        float ang = sqrtf(ex * ex + ey * ey + ez * ez);
        float inv = 1.f / ang;
        float ax = rx * inv, ay = ry * inv, az = rz * inv;
        float c = cosf(ang), s = sinf(ang), t = 1.f - c;
        // R = I + s*K + (1-c)*K^2
        mats[j][0]  = 1.f + t * (-(ay * ay + az * az));
        mats[j][1]  = -s * az + t * (ax * ay);
        mats[j][2]  =  s * ay + t * (ax * az);
        mats[j][4]  =  s * az + t * (ax * ay);
        mats[j][5]  = 1.f + t * (-(ax * ax + az * az));
        mats[j][6]  = -s * ax + t * (ay * az);
        mats[j][8]  = -s * ay + t * (ax * az);
        mats[j][9]  =  s * ax + t * (ay * az);
        mats[j][10] = 1.f + t * (-(ax * ax + ay * ay));
    }
    __syncthreads();
    if (j < NJ) {
        const int p = c_par[j];
        float t0 = sJ[j][0], t1 = sJ[j][1], t2 = sJ[j][2];
        if (p >= 0) { t0 -= sJ[p][0]; t1 -= sJ[p][1]; t2 -= sJ[p][2]; }
        mats[j][3] = t0; mats[j][7] = t1; mats[j][11] = t2;
    }
    __syncthreads();
    // serial chain compose on lane 0 (23 affine 3x4 compositions — trivial)
    if (threadIdx.x == 0) {
#pragma unroll
        for (int k = 0; k < 12; ++k) chain[0][k] = mats[0][k];
        for (int i = 1; i < NJ; ++i) {
            const int p = c_par[i];
#pragma unroll
            for (int r = 0; r < 3; ++r) {
#pragma unroll
                for (int col = 0; col < 4; ++col) {
                    float acc = (col == 3) ? chain[p][r * 4 + 3] : 0.f;
#pragma unroll
                    for (int q = 0; q < 3; ++q) acc = fmaf(chain[p][r * 4 + q], mats[i][q * 4 + col], acc);
                    chain[i][r * 4 + col] = acc;
                }
            }
        }
    }
    __syncthreads();
    if (j < NJ) {
        float A[12];
#pragma unroll
        for (int k = 0; k < 12; ++k) A[k] = chain[j][k];
        const float c0 = A[3], c1 = A[7], c2 = A[11];
        const float j0 = sJ[j][0], j1 = sJ[j][1], j2 = sJ[j][2];
        A[3]  = c0 - (A[0] * j0 + A[1] * j1 + A[2]  * j2);
        A[7]  = c1 - (A[4] * j0 + A[5] * j1 + A[6]  * j2);
        A[11] = c2 - (A[8] * j0 + A[9] * j1 + A[10] * j2);
#pragma unroll
        for (int k = 0; k < 12; ++k) wsA[((size_t)b * NJ + j) * 12 + k] = A[k];
        // posed joints + transl
        const float tx = transl[b * 3 + 0], ty = transl[b * 3 + 1], tz = transl[b * 3 + 2];
        const size_t o = ((size_t)b * NOUT + NV + j) * 3;
        out[o + 0] = c0 + tx; out[o + 1] = c1 + ty; out[o + 2] = c2 + tz;
    }
}

// ---------------------------------------------------------------------------
// Kernel C: LBS skinning — the dominant cost.
// grid (VBLK, BATCH/BPB), block 256; one vertex per thread, BPB batches per thread.
// A[b] is block-uniform: read via uniform __restrict pointer → expect s_load (SMEM),
// keeping the inner loop pure v_fmac. Per-vertex data (w, shapedirs, templates)
// lives in registers across the batch loop.
// ---------------------------------------------------------------------------
__global__ __launch_bounds__(256) void lbs_kernel(
    const float* __restrict__ betas,
    const float* __restrict__ transl,
    const float* __restrict__ msc,
    const float* __restrict__ smpl_t,
    const float* __restrict__ smil_t,
    const float* __restrict__ sdirs,
    const float* __restrict__ lbsw,
    const float* __restrict__ wsA,
    float* __restrict__ out)
{
    const int v = blockIdx.x * 256 + threadIdx.x;
    const bool valid = v < NV;
    const int vc = valid ? v : NV - 1;
    const int b0 = blockIdx.y * BPB;
    const float s = msc[0];

    // per-vertex, batch-independent data → registers
    float vt[3];
#pragma unroll
    for (int k = 0; k < 3; ++k)
        vt[k] = s * smpl_t[vc * 3 + k] + (1.f - s) * smil_t[vc * 3 + k];

    float sd[30];
    {
        const float2* sd2 = (const float2*)(sdirs + (size_t)vc * 30);
#pragma unroll
        for (int i = 0; i < 15; ++i) { float2 x = sd2[i]; sd[2 * i] = x.x; sd[2 * i + 1] = x.y; }
    }
    float w[NJ];
    {
        const float4* w4 = (const float4*)(lbsw + (size_t)vc * NJ);
#pragma unroll
        for (int i = 0; i < 6; ++i) {
            float4 x = w4[i];
            w[4 * i] = x.x; w[4 * i + 1] = x.y; w[4 * i + 2] = x.z; w[4 * i + 3] = x.w;
        }
    }

#pragma unroll
    for (int bb = 0; bb < BPB; ++bb) {
        const int b = b0 + bb;
        const float* __restrict__ Bb = betas + b * (NBD + 1);   // uniform
        const float* __restrict__ Ab = wsA + (size_t)b * NJ * 12; // uniform

        // v_shaped
        float vs[3];
#pragma unroll
        for (int k = 0; k < 3; ++k) {
            float a = vt[k];
#pragma unroll
            for (int l = 0; l < NBD; ++l) a = fmaf(Bb[1 + l], sd[k * 10 + l], a);
            vs[k] = a * Bb[0];
        }

        // T = sum_j w_j * A_j (3x4), A uniform → scalar operand in v_fmac
        float T[12];
#pragma unroll
        for (int k = 0; k < 12; ++k) T[k] = 0.f;
#pragma unroll 4
        for (int jj = 0; jj < NJ; ++jj) {
            const float ww = w[jj];
#pragma unroll
            for (int k = 0; k < 12; ++k) T[k] = fmaf(ww, Ab[jj * 12 + k], T[k]);
        }

        if (valid) {
            const float tx = transl[b * 3 + 0], ty = transl[b * 3 + 1], tz = transl[b * 3 + 2];
            const size_t o = ((size_t)b * NOUT + v) * 3;
            out[o + 0] = fmaf(T[0], vs[0], fmaf(T[1], vs[1], fmaf(T[2],  vs[2], T[3])))  + tx;
            out[o + 1] = fmaf(T[4], vs[0], fmaf(T[5], vs[1], fmaf(T[6],  vs[2], T[7])))  + ty;
            out[o + 2] = fmaf(T[8], vs[0], fmaf(T[9], vs[1], fmaf(T[10], vs[2], T[11]))) + tz;
        }
    }
}

// ---------------------------------------------------------------------------
// Kernel D: extra joints = J_regressor_extra @ (verts + transl).
// Softmax rows sum to 1, so regressing translated verts directly gives extra+t.
// grid BATCH, block 256; per-block reduction over V.
// ---------------------------------------------------------------------------
__global__ __launch_bounds__(256) void extra_kernel(
    const float* __restrict__ jre,
    float* out)
{
    const int b = blockIdx.x;
    const float* vb = out + (size_t)b * NOUT * 3;

    float acc[27];
#pragma unroll
    for (int i = 0; i < 27; ++i) acc[i] = 0.f;

    for (int v = threadIdx.x; v < NV; v += 256) {
        const float x = vb[v * 3 + 0], y = vb[v * 3 + 1], z = vb[v * 3 + 2];
#pragma unroll
        for (int e = 0; e < NEXTRA; ++e) {
            const float we = jre[e * NV + v];
            acc[e * 3 + 0] = fmaf(we, x, acc[e * 3 + 0]);
            acc[e * 3 + 1] = fmaf(we, y, acc[e * 3 + 1]);
            acc[e * 3 + 2] = fmaf(we, z, acc[e * 3 + 2]);
        }
    }

#pragma unroll
    for (int i = 0; i < 27; ++i) {
        float x = acc[i];
        for (int off = 32; off; off >>= 1) x += __shfl_xor(x, off, 64);
        acc[i] = x;
    }
    __shared__ float red[4][27];
    const int lane = threadIdx.x & 63, wv = threadIdx.x >> 6;
    if (lane == 0) {
#pragma unroll
        for (int i = 0; i < 27; ++i) red[wv][i] = acc[i];
    }
    __syncthreads();
    if (threadIdx.x < 27) {
        const float sum = red[0][threadIdx.x] + red[1][threadIdx.x]
                        + red[2][threadIdx.x] + red[3][threadIdx.x];
        out[((size_t)b * NOUT + NV + NJ) * 3 + threadIdx.x] = sum;
    }
}

// ---------------------------------------------------------------------------
extern "C" void kernel_launch(void* const* d_in, const int* in_sizes, int n_in,
                              void* d_out, int out_size, void* d_ws, size_t ws_size,
                              hipStream_t stream) {
    const float* betas     = (const float*)d_in[0];
    const float* body_pose = (const float*)d_in[1];
    const float* glob_or   = (const float*)d_in[2];
    const float* transl    = (const float*)d_in[3];
    const float* msc       = (const float*)d_in[4];
    const float* smpl_t    = (const float*)d_in[5];
    const float* smil_t    = (const float*)d_in[6];
    const float* sdirs     = (const float*)d_in[7];
    const float* jreg      = (const float*)d_in[8];
    const float* lbsw      = (const float*)d_in[9];
    const float* jre       = (const float*)d_in[10];
    // d_in[11] = parents (hard-coded in c_par)

    float* out  = (float*)d_out;
    float* ws   = (float*)d_ws;
    float* jtjs = ws;                 // NJ*33 = 792 floats
    float* wsA  = ws + 792;           // BATCH*NJ*12 = 147456 floats

    // zero the atomic accumulator region (ws is poisoned 0xAA before each call)
    hipMemsetAsync(jtjs, 0, NJ * 33 * sizeof(float), stream);

    dim3 gA(VBLK, NJ);
    precompute_kernel<<<gA, 256, 0, stream>>>(jreg, smpl_t, smil_t, sdirs, msc, jtjs);

    joints_kernel<<<BATCH, 64, 0, stream>>>(betas, body_pose, glob_or, transl, jtjs, wsA, out);

    dim3 gC(VBLK, BATCH / BPB);
    lbs_kernel<<<gC, 256, 0, stream>>>(betas, transl, msc, smpl_t, smil_t, sdirs, lbsw, wsA, out);

    extra_kernel<<<BATCH, 256, 0, stream>>>(jre, out);
}